// Round 5
// baseline (4035.833 us; speedup 1.0000x reference)
//
#include <hip/hip_runtime.h>

#define TWO_PI 6.283185307179586f

struct Meta {
    int bz[7], by[7], bxm[7], bix[7], biz[7], bcv[7];  // block prefix per batched kernel
    int n[6], l1[6], L[6], NT[6];
    int soff[6];                // xy-site offsets: prefix of 8*n*n
    int tAo[6], tBo[6], tDo[6]; // float2 offsets for FT temporaries
};

__device__ __forceinline__ int find_lev(const int* pre) {
    int lev = 0;
    #pragma unroll
    for (int i = 1; i < 6; ++i) lev += (int)(blockIdx.x >= (unsigned)pre[i]);
    return lev;
}

// ---------------- wavelet decompose: x[b,2n,2n,64,9] -> d,s [b,n,n,64,9] ----------------
__global__ void wavelet_kernel(const float* __restrict__ x,
                               float* __restrict__ d, float* __restrict__ s,
                               const float* __restrict__ ec_d,
                               const float* __restrict__ ec_s,
                               int n, int total)
{
    __shared__ float wd[324], wsm[324];
    for (int i = threadIdx.x; i < 324; i += blockDim.x) { wd[i] = ec_d[i]; wsm[i] = ec_s[i]; }
    __syncthreads();
    int idx = blockIdx.x * blockDim.x + threadIdx.x;
    if (idx >= total) return;
    int it = idx & 63; int tmp = idx >> 6;
    int iy = tmp % n; tmp /= n;
    int ix = tmp % n; int b = tmp / n;
    int n2 = 2 * n;
    const float* base = x + ((((size_t)(b * n2 + 2 * ix) * n2 + 2 * iy) * 64 + it) * 9);
    const float* p0 = base;
    const float* p1 = base + 64 * 9;
    const float* p2 = base + (size_t)n2 * 64 * 9;
    const float* p3 = p2 + 64 * 9;
    float a[36];
    #pragma unroll
    for (int k = 0; k < 9; ++k) { a[k] = p0[k]; a[9+k] = p1[k]; a[18+k] = p2[k]; a[27+k] = p3[k]; }
    size_t ob = (size_t)idx * 9;
    #pragma unroll
    for (int oc = 0; oc < 9; ++oc) {
        float vd = 0.f, vs = 0.f;
        #pragma unroll
        for (int k = 0; k < 36; ++k) { vd += a[k] * wd[k*9+oc]; vs += a[k] * wsm[k*9+oc]; }
        d[ob+oc] = vd; s[ob+oc] = vs;
    }
}

// ------------- dual conv3d(3,SAME) + bias + ReLU + Linear, 2 iy-sites per thread -------------
// all levels batched; blockIdx.y==0: B-conv s->Ud(+=), ==1: C-conv d->Us(=)
__global__ void conv2_kernel(const float* __restrict__ s_all, float* __restrict__ ud_all,
                             const float* __restrict__ d_all, float* __restrict__ us_all,
                             const float* __restrict__ Bcw, const float* __restrict__ Bcb,
                             const float* __restrict__ Blw, const float* __restrict__ Blb,
                             const float* __restrict__ Ccw, const float* __restrict__ Ccb,
                             const float* __restrict__ Clw, const float* __restrict__ Clb,
                             Meta m)
{
    const int which = blockIdx.y;
    const float* cw = which ? Ccw : Bcw;
    const float* cb = which ? Ccb : Bcb;
    const float* lw = which ? Clw : Blw;
    const float* lb = which ? Clb : Blb;

    __shared__ float scw2[2430];   // [wo(27)][o(9)][ic pad 10]
    __shared__ float slw[81], scb[9], slb[9];
    for (int i = threadIdx.x; i < 2187; i += 256) {
        int wo = i / 81, rem = i % 81, o = rem / 9, ic = rem % 9;
        scw2[(wo * 9 + o) * 10 + ic] = cw[(o * 9 + ic) * 27 + wo];
    }
    if (threadIdx.x < 81) slw[threadIdx.x] = lw[threadIdx.x];
    if (threadIdx.x < 9) { scb[threadIdx.x] = cb[threadIdx.x]; slb[threadIdx.x] = lb[threadIdx.x]; }
    __syncthreads();

    int lev = find_lev(m.bcv);
    int n = m.n[lev];
    int idx = (blockIdx.x - m.bcv[lev]) * 256 + threadIdx.x;
    int nh = (n + 1) >> 1;
    int total = 8 * n * nh * 64;
    if (idx >= total) return;
    int t = idx & 63; int tmp = idx >> 6;
    int iy0 = (tmp % nh) * 2; tmp /= nh;
    int ix = tmp % n; int b = tmp / n;
    bool s1ok = (iy0 + 1) < n;
    const float* in = (which ? d_all : s_all) + (size_t)m.soff[lev] * 576;
    float* out      = (which ? us_all : ud_all) + (size_t)m.soff[lev] * 576;

    float acc0[9], acc1[9];
    #pragma unroll
    for (int o = 0; o < 9; ++o) { acc0[o] = scb[o]; acc1[o] = scb[o]; }

    for (int dx = -1; dx <= 1; ++dx) {
        int jx = ix + dx; bool okx = (unsigned)jx < (unsigned)n;
        for (int dt = -1; dt <= 1; ++dt) {
            int jt = t + dt; bool okt = (unsigned)jt < 64u;
            float v[4][9];
            #pragma unroll
            for (int r = 0; r < 4; ++r) {
                int jy = iy0 - 1 + r;
                bool ok = okx && okt && ((unsigned)jy < (unsigned)n);
                const float* p = in + (((size_t)(b * n + jx) * n + jy) * 64 + jt) * 9;
                #pragma unroll
                for (int ic = 0; ic < 9; ++ic) v[r][ic] = ok ? p[ic] : 0.f;
            }
            #pragma unroll
            for (int dy = 0; dy < 3; ++dy) {
                const float* wbase = &scw2[((dx + 1) * 9 + dy * 3 + (dt + 1)) * 90];
                #pragma unroll
                for (int o = 0; o < 9; ++o) {
                    const float* wp = wbase + o * 10;
                    float2 w01 = *(const float2*)(wp);
                    float2 w23 = *(const float2*)(wp + 2);
                    float2 w45 = *(const float2*)(wp + 4);
                    float2 w67 = *(const float2*)(wp + 6);
                    float  w8  = wp[8];
                    const float* a = v[dy];
                    const float* c = v[dy + 1];
                    acc0[o] += a[0]*w01.x + a[1]*w01.y + a[2]*w23.x + a[3]*w23.y
                             + a[4]*w45.x + a[5]*w45.y + a[6]*w67.x + a[7]*w67.y + a[8]*w8;
                    acc1[o] += c[0]*w01.x + c[1]*w01.y + c[2]*w23.x + c[3]*w23.y
                             + c[4]*w45.x + c[5]*w45.y + c[6]*w67.x + c[7]*w67.y + c[8]*w8;
                }
            }
        }
    }
    #pragma unroll
    for (int s = 0; s < 2; ++s) {
        if (s == 1 && !s1ok) break;
        float r[9];
        #pragma unroll
        for (int o = 0; o < 9; ++o) r[o] = fmaxf(s ? acc1[o] : acc0[o], 0.f);
        size_t ob = (((size_t)(b * n + ix) * n + iy0 + s) * 64 + t) * 9;
        #pragma unroll
        for (int o2 = 0; o2 < 9; ++o2) {
            float vv = slb[o2];
            #pragma unroll
            for (int o = 0; o < 9; ++o) vv += r[o] * slw[o2 * 9 + o];
            if (which == 0) out[ob + o2] += vv; else out[ob + o2] = vv;
        }
    }
}

// ---------------- forward z DFT (all levels): d -> tA [site,kz(5),ic(9)] ----------------
__global__ void fwdz_kernel(const float* __restrict__ d_all, float2* __restrict__ tA, Meta m)
{
    int lev = find_lev(m.bz);
    int n = m.n[lev];
    int idx = (blockIdx.x - m.bz[lev]) * 256 + threadIdx.x;
    int total = 8 * n * n * 45;
    if (idx >= total) return;
    int ic = idx % 9; int tmp = idx / 9;
    int kz = tmp % 5; int site = tmp / 5;
    const float* p = d_all + (size_t)(m.soff[lev] + site) * 576 + ic;
    float re = 0.f, im = 0.f;
    for (int it = 0; it < 64; ++it) {
        int mm = (kz * it) & 63;
        float sv, cv; __sincosf((TWO_PI / 64.0f) * mm, &sv, &cv);
        float v = p[(size_t)it * 9];
        re += v * cv; im -= v * sv;
    }
    tA[m.tAo[lev] + idx] = make_float2(re, im);
}

// ---------------- forward y DFT (kept modes only, all levels) ----------------
__global__ void fwdy_kernel(const float2* __restrict__ tA, float2* __restrict__ tB, Meta m)
{
    int lev = find_lev(m.by);
    int n = m.n[lev], l1 = m.l1[lev], L = m.L[lev];
    int idx = (blockIdx.x - m.by[lev]) * 256 + threadIdx.x;
    int total = 8 * n * L * 45;
    if (idx >= total) return;
    int c45 = idx % 45; int tmp = idx / 45;
    int kyI = tmp % L; tmp /= L;
    int ix = tmp % n; int b = tmp / n;
    int ky = (kyI < l1) ? kyI : (n - L + kyI);
    const float2* p = tA + m.tAo[lev] + ((size_t)(b * n + ix) * n) * 45 + c45;
    float re = 0.f, im = 0.f;
    for (int iy = 0; iy < n; ++iy) {
        int mm = (ky * iy) & (n - 1);
        float sv, cv; __sincosf((TWO_PI / n) * mm, &sv, &cv);
        float2 a = p[(size_t)iy * 45];
        re += a.x * cv + a.y * sv;
        im += a.y * cv - a.x * sv;
    }
    tB[m.tBo[lev] + idx] = make_float2(re, im);
}

// ------- fused forward-x DFT + 9x9 complex mode mix (priority w4>w3>w2>w1), all levels -------
__global__ void fwdxmix_kernel(const float2* __restrict__ tB, float2* __restrict__ tD,
                               const float* __restrict__ w1, const float* __restrict__ w2,
                               const float* __restrict__ w3, const float* __restrict__ w4,
                               Meta m)
{
    __shared__ float2 sFzy[32 * 45];
    __shared__ float2 sF[10 * 45];
    int lev = find_lev(m.bxm);
    int n = m.n[lev], l1 = m.l1[lev], L = m.L[lev];
    int lb = blockIdx.x - m.bxm[lev];
    int kyI = lb % L;
    int b   = lb / L;
    int ky = (kyI < l1) ? kyI : (n - L + kyI);
    int nload = n * 45;
    for (int i = threadIdx.x; i < nload; i += blockDim.x) {
        int ix = i / 45, c = i % 45;
        sFzy[i] = tB[m.tBo[lev] + ((size_t)(b * n + ix) * L + kyI) * 45 + c];
    }
    __syncthreads();
    int nf = L * 45;
    for (int i = threadIdx.x; i < nf; i += blockDim.x) {
        int kxI = i / 45, c = i % 45;
        int kx = (kxI < l1) ? kxI : (n - L + kxI);
        float re = 0.f, im = 0.f;
        for (int ix = 0; ix < n; ++ix) {
            int mm = (kx * ix) & (n - 1);
            float sv, cv; __sincosf((TWO_PI / n) * mm, &sv, &cv);
            float2 a = sFzy[ix * 45 + c];
            re += a.x * cv + a.y * sv;
            im += a.y * cv - a.x * sv;
        }
        sF[i] = make_float2(re, im);
    }
    __syncthreads();
    bool ly = ky < l1, hy = ky >= n - l1;
    for (int i = threadIdx.x; i < nf; i += blockDim.x) {
        int kxI = i / 45, c = i % 45;
        int kz = c / 9, oc = c % 9;
        int kx = (kxI < l1) ? kxI : (n - L + kxI);
        bool lx = kx < l1, hx = kx >= n - l1;
        const float* w; int wx, wy;
        if (hx && hy)      { w = w4; wx = kx - (n - l1); wy = ky - (n - l1); }
        else if (lx && hy) { w = w3; wx = kx;            wy = ky - (n - l1); }
        else if (hx && ly) { w = w2; wx = kx - (n - l1); wy = ky; }
        else               { w = w1; wx = kx;            wy = ky; }
        const float* wb = w + (((size_t)oc * 5 + wx) * 5 + wy) * 10 + kz * 2;
        const float2* pf = &sF[kxI * 45 + kz * 9];
        float re = 0.f, im = 0.f;
        #pragma unroll
        for (int ic = 0; ic < 9; ++ic) {
            float2 a = pf[ic];
            float wr = wb[(size_t)ic * 2250];
            float wi = wb[(size_t)ic * 2250 + 1];
            re += a.x * wr - a.y * wi;
            im += a.x * wi + a.y * wr;
        }
        tD[m.tDo[lev] + (((size_t)(b * L + kxI) * L + kyI) * 5 + kz) * 9 + oc] = make_float2(re, im);
    }
}

// ---------------- inverse x (zero-padded modes -> full axis), all levels ----------------
__global__ void invx_kernel(const float2* __restrict__ tD, float2* __restrict__ tB, Meta m)
{
    int lev = find_lev(m.bix);
    int n = m.n[lev], l1 = m.l1[lev], L = m.L[lev];
    int idx = (blockIdx.x - m.bix[lev]) * 256 + threadIdx.x;
    int total = 8 * n * L * 45;
    if (idx >= total) return;
    int c45 = idx % 45; int tmp = idx / 45;
    int kyI = tmp % L; tmp /= L;
    int ix = tmp % n; int b = tmp / n;
    const float2* p = tD + m.tDo[lev] + ((size_t)b * L * L) * 45 + (size_t)kyI * 45 + c45;
    float re = 0.f, im = 0.f;
    for (int kxI = 0; kxI < L; ++kxI) {
        int kx = (kxI < l1) ? kxI : (n - L + kxI);
        int mm = (kx * ix) & (n - 1);
        float sv, cv; __sincosf((TWO_PI / n) * mm, &sv, &cv);
        float2 a = p[(size_t)kxI * L * 45];
        re += a.x * cv - a.y * sv;
        im += a.x * sv + a.y * cv;
    }
    tB[m.tBo[lev] + idx] = make_float2(re, im);
}

// ------- fused inverse-y + inverse-z(c2r) + ReLU + Linear, all levels -------
__global__ void invyz_kernel(const float2* __restrict__ tB, float* __restrict__ ud_all,
                             const float* __restrict__ lw, const float* __restrict__ lb,
                             Meta m)
{
    __shared__ float2 sG1[10 * 45];
    __shared__ float2 sG2[4 * 45];
    __shared__ float slw[81], slb[9];
    int lev = find_lev(m.biz);
    int n = m.n[lev], l1 = m.l1[lev], L = m.L[lev], NT = m.NT[lev];
    int TY = n / NT;
    int lb2 = blockIdx.x - m.biz[lev];
    int iyt = lb2 % NT;
    int ix  = (lb2 / NT) % n;
    int b   = lb2 / (NT * n);
    int iy0 = iyt * TY;
    if (threadIdx.x < 81) slw[threadIdx.x] = lw[threadIdx.x];
    if (threadIdx.x < 9)  slb[threadIdx.x] = lb[threadIdx.x];
    int nload = L * 45;
    for (int i = threadIdx.x; i < nload; i += blockDim.x)
        sG1[i] = tB[m.tBo[lev] + ((size_t)(b * n + ix) * L) * 45 + i];
    __syncthreads();
    int nf = TY * 45;
    for (int i = threadIdx.x; i < nf; i += blockDim.x) {
        int il = i / 45, c = i % 45;
        int iy = iy0 + il;
        float re = 0.f, im = 0.f;
        for (int kyI = 0; kyI < L; ++kyI) {
            int ky = (kyI < l1) ? kyI : (n - L + kyI);
            int mm = (ky * iy) & (n - 1);
            float sv, cv; __sincosf((TWO_PI / n) * mm, &sv, &cv);
            float2 a = sG1[kyI * 45 + c];
            re += a.x * cv - a.y * sv;
            im += a.x * sv + a.y * cv;
        }
        sG2[i] = make_float2(re, im);
    }
    __syncthreads();
    int t = threadIdx.x;
    if (t < TY * 64) {
        int il = t >> 6, it = t & 63;
        float inv_norm = 1.0f / ((float)n * (float)n * 64.0f);
        float cvz[5], svz[5];
        #pragma unroll
        for (int kz = 0; kz < 5; ++kz) {
            int mm = (kz * it) & 63;
            __sincosf((TWO_PI / 64.0f) * mm, &svz[kz], &cvz[kz]);
        }
        const float2* pg = &sG2[il * 45];
        float y[9];
        #pragma unroll
        for (int oc = 0; oc < 9; ++oc) {
            float v = 0.f;
            #pragma unroll
            for (int kz = 0; kz < 5; ++kz) {
                float2 a = pg[kz * 9 + oc];
                float term = a.x * cvz[kz] - a.y * svz[kz];
                v += (kz == 0 ? 1.0f : 2.0f) * term;
            }
            y[oc] = fmaxf(v * inv_norm, 0.f);
        }
        size_t ob = ((size_t)(m.soff[lev] + (b * n + ix) * n + iy0 + il) * 64 + it) * 9;
        #pragma unroll
        for (int o2 = 0; o2 < 9; ++o2) {
            float v = slb[o2];
            #pragma unroll
            for (int oc = 0; oc < 9; ++oc) v += y[oc] * slw[o2 * 9 + oc];
            ud_all[ob + o2] = v;
        }
    }
}

// ------- reconstruct: (x(+T0)+Us | Ud) -> even/odd interleave to [b,2n,2n,64,9] -------
__global__ void recon_kernel(const float* __restrict__ x, const float* __restrict__ Us,
                             const float* __restrict__ Ud, float* __restrict__ out,
                             const float* __restrict__ ree, const float* __restrict__ reo,
                             const float* __restrict__ roe, const float* __restrict__ roo,
                             const float* __restrict__ t0w, const float* __restrict__ t0b,
                             int n, int total, int apply_t0)
{
    __shared__ float s_m[4][162];
    __shared__ float st0[81], st0b[9];
    for (int i = threadIdx.x; i < 162; i += blockDim.x) {
        s_m[0][i] = ree[i]; s_m[1][i] = reo[i]; s_m[2][i] = roe[i]; s_m[3][i] = roo[i];
    }
    if (threadIdx.x < 81) st0[threadIdx.x] = t0w[threadIdx.x];
    if (threadIdx.x < 9)  st0b[threadIdx.x] = t0b[threadIdx.x];
    __syncthreads();
    int idx = blockIdx.x * blockDim.x + threadIdx.x;
    if (idx >= total) return;
    int it = idx & 63; int tmp = idx >> 6;
    int iy = tmp % n; tmp /= n;
    int ix = tmp % n; int b = tmp / n;
    float v[18];
    size_t ib = (size_t)idx * 9;
    if (apply_t0) {
        float xr[9];
        #pragma unroll
        for (int k = 0; k < 9; ++k) xr[k] = x[ib+k];
        #pragma unroll
        for (int o = 0; o < 9; ++o) {
            float r = st0b[o];
            #pragma unroll
            for (int i = 0; i < 9; ++i) r += xr[i] * st0[o*9+i];
            v[o] = r + Us[ib+o];
        }
    } else {
        #pragma unroll
        for (int k = 0; k < 9; ++k) v[k] = x[ib+k] + Us[ib+k];
    }
    #pragma unroll
    for (int k = 0; k < 9; ++k) v[9+k] = Ud[ib+k];
    int n2 = 2 * n;
    #pragma unroll
    for (int q = 0; q < 4; ++q) {
        int rx = q >> 1, ry = q & 1;
        size_t ob = ((((size_t)(b * n2 + 2*ix + rx) * n2) + 2*iy + ry) * 64 + it) * 9;
        const float* mm = s_m[q];
        #pragma unroll
        for (int oc = 0; oc < 9; ++oc) {
            float r = 0.f;
            #pragma unroll
            for (int k = 0; k < 18; ++k) r += v[k] * mm[k*9+oc];
            out[ob + oc] = r;
        }
    }
}

extern "C" void kernel_launch(void* const* d_in, const int* in_sizes, int n_in,
                              void* d_out, int out_size, void* d_ws, size_t ws_size,
                              hipStream_t stream)
{
    const float* x0    = (const float*)d_in[0];
    const float* ec_s  = (const float*)d_in[1];
    const float* ec_d  = (const float*)d_in[2];
    const float* rc_ee = (const float*)d_in[3];
    const float* rc_eo = (const float*)d_in[4];
    const float* rc_oe = (const float*)d_in[5];
    const float* rc_oo = (const float*)d_in[6];
    const float* w1    = (const float*)d_in[7];
    const float* w2    = (const float*)d_in[8];
    const float* w3    = (const float*)d_in[9];
    const float* w4    = (const float*)d_in[10];
    const float* A_Lo_w = (const float*)d_in[11];
    const float* A_Lo_b = (const float*)d_in[12];
    const float* B_cw  = (const float*)d_in[13];
    const float* B_cb  = (const float*)d_in[14];
    const float* B_lw  = (const float*)d_in[15];
    const float* B_lb  = (const float*)d_in[16];
    const float* C_cw  = (const float*)d_in[17];
    const float* C_cb  = (const float*)d_in[18];
    const float* C_lw  = (const float*)d_in[19];
    const float* C_lb  = (const float*)d_in[20];
    const float* T0_w  = (const float*)d_in[21];
    const float* T0_b  = (const float*)d_in[22];

    // ---- build meta ----
    Meta m;
    int ns_[6] = {32, 16, 8, 4, 2, 1};
    int az = 0, ay = 0, axm = 0, aix = 0, aiz = 0, acv = 0;
    int aS = 0, aA = 0, aB = 0, aD = 0;
    for (int l = 0; l < 6; ++l) {
        int n = ns_[l];
        int l1 = (n / 2 + 1 < 5) ? (n / 2 + 1) : 5;
        int L = (2 * l1 < n) ? 2 * l1 : n;
        int TY = (n < 4) ? n : 4;
        int NT = n / TY;
        int nh = (n + 1) / 2;
        m.n[l] = n; m.l1[l] = l1; m.L[l] = L; m.NT[l] = NT;
        m.soff[l] = aS; m.tAo[l] = aA; m.tBo[l] = aB; m.tDo[l] = aD;
        m.bz[l] = az; m.by[l] = ay; m.bxm[l] = axm; m.bix[l] = aix; m.biz[l] = aiz; m.bcv[l] = acv;
        az  += (8 * n * n * 45 + 255) / 256;
        ay  += (8 * n * L * 45 + 255) / 256;
        axm += 8 * L;
        aix += (8 * n * L * 45 + 255) / 256;
        aiz += 8 * n * NT;
        acv += (8 * n * nh * 64 + 255) / 256;
        aS += 8 * n * n; aA += 8 * n * n * 45; aB += 8 * n * L * 45; aD += 8 * L * L * 45;
    }
    m.bz[6] = az; m.by[6] = ay; m.bxm[6] = axm; m.bix[6] = aix; m.biz[6] = aiz; m.bcv[6] = acv;

    // ---- workspace carve ----
    float* ws = (float*)d_ws;
    size_t off = 0;
    auto alloc = [&](size_t nf) { float* p = ws + off; off += (nf + 3) & ~(size_t)3; return p; };
    size_t NSf = (size_t)aS * 576;      // total d/s/Ud/Us floats
    float* d_all  = alloc(NSf);
    float* s_all  = alloc(NSf);
    float* ud_all = alloc(NSf);
    float* us_all = alloc(NSf);
    float2* tA = (float2*)alloc((size_t)aA * 2);
    float2* tB = (float2*)alloc((size_t)aB * 2);
    float2* tD = (float2*)alloc((size_t)aD * 2);
    float* pingA = alloc((size_t)8 * 32 * 32 * 64 * 9);  // lev5,3,1 outputs (max 18.9MB)
    float* pingB = alloc((size_t)8 * 16 * 16 * 64 * 9);  // lev4,2 outputs

    const int BLK = 256;

    // ---- decompose chain (sequential) ----
    for (int lev = 0; lev < 6; ++lev) {
        int n = ns_[lev];
        const float* xin = (lev == 0) ? x0 : (s_all + (size_t)m.soff[lev-1] * 576);
        int total = 8 * n * n * 64;
        wavelet_kernel<<<(total + BLK - 1) / BLK, BLK, 0, stream>>>(
            xin, d_all + (size_t)m.soff[lev] * 576, s_all + (size_t)m.soff[lev] * 576,
            ec_d, ec_s, n, total);
    }

    // ---- batched FT pipeline + convs (all levels in one dispatch each) ----
    fwdz_kernel  <<<az,  BLK, 0, stream>>>(d_all, tA, m);
    fwdy_kernel  <<<ay,  BLK, 0, stream>>>(tA, tB, m);
    fwdxmix_kernel<<<axm, BLK, 0, stream>>>(tB, tD, w1, w2, w3, w4, m);
    invx_kernel  <<<aix, BLK, 0, stream>>>(tD, tB, m);
    invyz_kernel <<<aiz, BLK, 0, stream>>>(tB, ud_all, A_Lo_w, A_Lo_b, m);
    dim3 cgrid(acv, 2);
    conv2_kernel <<<cgrid, BLK, 0, stream>>>(s_all, ud_all, d_all, us_all,
                                             B_cw, B_cb, B_lw, B_lb,
                                             C_cw, C_cb, C_lw, C_lb, m);

    // ---- reconstruct chain (sequential; lev5 applies T0 inline) ----
    float* cur = nullptr;
    for (int lev = 5; lev >= 0; --lev) {
        int n = ns_[lev];
        int total = 8 * n * n * 64;
        const float* xin = (lev == 5) ? (s_all + (size_t)m.soff[5] * 576) : cur;
        float* outp = (lev == 0) ? (float*)d_out : ((lev & 1) ? pingA : pingB);
        recon_kernel<<<(total + BLK - 1) / BLK, BLK, 0, stream>>>(
            xin, us_all + (size_t)m.soff[lev] * 576, ud_all + (size_t)m.soff[lev] * 576, outp,
            rc_ee, rc_eo, rc_oe, rc_oo, T0_w, T0_b, n, total, (lev == 5) ? 1 : 0);
        cur = outp;
    }
}

// Round 10
// 577.430 us; speedup vs baseline: 6.9893x; 6.9893x over previous
//
#include <hip/hip_runtime.h>

#define TWO_PI 6.283185307179586f

struct Meta {
    int bz[7], by[7], bxm[7], bix[7], biz[7], bcv[7];  // block prefix per batched kernel
    int n[6], l1[6], L[6], NT[6];
    int soff[6];                // xy-site offsets: prefix of 8*n*n
    int tAo[6], tBo[6], tDo[6]; // float2 offsets for FT temporaries
};

__device__ __forceinline__ int find_lev(const int* pre) {
    int lev = 0;
    #pragma unroll
    for (int i = 1; i < 6; ++i) lev += (int)(blockIdx.x >= (unsigned)pre[i]);
    return lev;
}

// ---------------- wavelet decompose: x[b,2n,2n,64,9] -> d,s [b,n,n,64,9] ----------------
__global__ void wavelet_kernel(const float* __restrict__ x,
                               float* __restrict__ d, float* __restrict__ s,
                               const float* __restrict__ ec_d,
                               const float* __restrict__ ec_s,
                               int n, int total)
{
    __shared__ float wd[324], wsm[324];
    for (int i = threadIdx.x; i < 324; i += blockDim.x) { wd[i] = ec_d[i]; wsm[i] = ec_s[i]; }
    __syncthreads();
    int idx = blockIdx.x * blockDim.x + threadIdx.x;
    if (idx >= total) return;
    int it = idx & 63; int tmp = idx >> 6;
    int iy = tmp % n; tmp /= n;
    int ix = tmp % n; int b = tmp / n;
    int n2 = 2 * n;
    const float* base = x + ((((size_t)(b * n2 + 2 * ix) * n2 + 2 * iy) * 64 + it) * 9);
    const float* p0 = base;
    const float* p1 = base + 64 * 9;
    const float* p2 = base + (size_t)n2 * 64 * 9;
    const float* p3 = p2 + 64 * 9;
    float a[36];
    #pragma unroll
    for (int k = 0; k < 9; ++k) { a[k] = p0[k]; a[9+k] = p1[k]; a[18+k] = p2[k]; a[27+k] = p3[k]; }
    size_t ob = (size_t)idx * 9;
    #pragma unroll
    for (int oc = 0; oc < 9; ++oc) {
        float vd = 0.f, vs = 0.f;
        #pragma unroll
        for (int k = 0; k < 36; ++k) { vd += a[k] * wd[k*9+oc]; vs += a[k] * wsm[k*9+oc]; }
        d[ob+oc] = vd; s[ob+oc] = vs;
    }
}

// ------------- dual conv3d(3,SAME) + bias + ReLU + Linear, 2 iy-sites per thread -------------
// rolling 2-row window (va/vb) keeps live state ~60 VGPRs -> no scratch spill.
// blockIdx.y==0: B-conv s->Ud(+=), ==1: C-conv d->Us(=)
__global__ __launch_bounds__(256, 2)
void conv2_kernel(const float* __restrict__ s_all, float* __restrict__ ud_all,
                  const float* __restrict__ d_all, float* __restrict__ us_all,
                  const float* __restrict__ Bcw, const float* __restrict__ Bcb,
                  const float* __restrict__ Blw, const float* __restrict__ Blb,
                  const float* __restrict__ Ccw, const float* __restrict__ Ccb,
                  const float* __restrict__ Clw, const float* __restrict__ Clb,
                  Meta m)
{
    const int which = blockIdx.y;
    const float* cw = which ? Ccw : Bcw;
    const float* cb = which ? Ccb : Bcb;
    const float* lw = which ? Clw : Blw;
    const float* lb = which ? Clb : Blb;

    __shared__ float scw2[2430];   // [wo(27)][o(9)][ic pad 10]
    __shared__ float slw[81], scb[9], slb[9];
    for (int i = threadIdx.x; i < 2187; i += 256) {
        int wo = i / 81, rem = i % 81, o = rem / 9, ic = rem % 9;
        scw2[(wo * 9 + o) * 10 + ic] = cw[(o * 9 + ic) * 27 + wo];
    }
    if (threadIdx.x < 81) slw[threadIdx.x] = lw[threadIdx.x];
    if (threadIdx.x < 9) { scb[threadIdx.x] = cb[threadIdx.x]; slb[threadIdx.x] = lb[threadIdx.x]; }
    __syncthreads();

    int lev = find_lev(m.bcv);
    int n = m.n[lev];
    int idx = (blockIdx.x - m.bcv[lev]) * 256 + threadIdx.x;
    int nh = (n + 1) >> 1;
    int total = 8 * n * nh * 64;
    if (idx >= total) return;
    int t = idx & 63; int tmp = idx >> 6;
    int iy0 = (tmp % nh) * 2; tmp /= nh;
    int ix = tmp % n; int b = tmp / n;
    bool has1 = (iy0 + 1) < n;
    const float* in = (which ? d_all : s_all) + (size_t)m.soff[lev] * 576;
    float* out      = (which ? us_all : ud_all) + (size_t)m.soff[lev] * 576;

    float acc0[9], acc1[9];
    #pragma unroll
    for (int o = 0; o < 9; ++o) { acc0[o] = scb[o]; acc1[o] = scb[o]; }

    for (int dd = 0; dd < 9; ++dd) {
        int dx = dd / 3 - 1, dt = dd % 3 - 1;
        int jx = ix + dx, jt = t + dt;
        bool okxt = ((unsigned)jx < (unsigned)n) && ((unsigned)jt < 64u);
        const float* rowbase = in + (((size_t)(b * n + (okxt ? jx : 0)) * n) * 64
                                     + (okxt ? jt : 0)) * 9;
        float va[9], vb[9];
        {   // va = row(iy0-1), vb = row(iy0)
            int jy = iy0 - 1; bool ok = okxt && (jy >= 0);
            const float* p = rowbase + (size_t)(ok ? jy : 0) * 576;
            #pragma unroll
            for (int ic = 0; ic < 9; ++ic) va[ic] = ok ? p[ic] : 0.f;
            const float* q = rowbase + (size_t)iy0 * 576;
            #pragma unroll
            for (int ic = 0; ic < 9; ++ic) vb[ic] = okxt ? q[ic] : 0.f;
        }
        #pragma unroll
        for (int k = 0; k < 3; ++k) {
            const float* wbase = &scw2[(((dx + 1) * 3 + k) * 3 + (dt + 1)) * 90];
            #pragma unroll
            for (int o = 0; o < 9; ++o) {
                const float* wp = wbase + o * 10;
                float2 w01 = *(const float2*)(wp);
                float2 w23 = *(const float2*)(wp + 2);
                float2 w45 = *(const float2*)(wp + 4);
                float2 w67 = *(const float2*)(wp + 6);
                float  w8  = wp[8];
                acc0[o] += va[0]*w01.x + va[1]*w01.y + va[2]*w23.x + va[3]*w23.y
                         + va[4]*w45.x + va[5]*w45.y + va[6]*w67.x + va[7]*w67.y + va[8]*w8;
                acc1[o] += vb[0]*w01.x + vb[1]*w01.y + vb[2]*w23.x + vb[3]*w23.y
                         + vb[4]*w45.x + vb[5]*w45.y + vb[6]*w67.x + vb[7]*w67.y + vb[8]*w8;
            }
            if (k < 2) {
                int jy = iy0 + k + 1; bool ok = okxt && (jy < n);
                const float* p = rowbase + (size_t)(ok ? jy : 0) * 576;
                #pragma unroll
                for (int ic = 0; ic < 9; ++ic) { va[ic] = vb[ic]; vb[ic] = ok ? p[ic] : 0.f; }
            }
        }
    }
    {   // site iy0
        float r[9];
        #pragma unroll
        for (int o = 0; o < 9; ++o) r[o] = fmaxf(acc0[o], 0.f);
        size_t ob = (((size_t)(b * n + ix) * n + iy0) * 64 + t) * 9;
        #pragma unroll
        for (int o2 = 0; o2 < 9; ++o2) {
            float vv = slb[o2];
            #pragma unroll
            for (int o = 0; o < 9; ++o) vv += r[o] * slw[o2 * 9 + o];
            if (which == 0) out[ob + o2] += vv; else out[ob + o2] = vv;
        }
    }
    if (has1) {  // site iy0+1
        float r[9];
        #pragma unroll
        for (int o = 0; o < 9; ++o) r[o] = fmaxf(acc1[o], 0.f);
        size_t ob = (((size_t)(b * n + ix) * n + iy0 + 1) * 64 + t) * 9;
        #pragma unroll
        for (int o2 = 0; o2 < 9; ++o2) {
            float vv = slb[o2];
            #pragma unroll
            for (int o = 0; o < 9; ++o) vv += r[o] * slw[o2 * 9 + o];
            if (which == 0) out[ob + o2] += vv; else out[ob + o2] = vv;
        }
    }
}

// ---------------- forward z DFT (all levels): d -> tA [site,kz(5),ic(9)] ----------------
__global__ void fwdz_kernel(const float* __restrict__ d_all, float2* __restrict__ tA, Meta m)
{
    int lev = find_lev(m.bz);
    int n = m.n[lev];
    int idx = (blockIdx.x - m.bz[lev]) * 256 + threadIdx.x;
    int total = 8 * n * n * 45;
    if (idx >= total) return;
    int ic = idx % 9; int tmp = idx / 9;
    int kz = tmp % 5; int site = tmp / 5;
    const float* p = d_all + (size_t)(m.soff[lev] + site) * 576 + ic;
    float re = 0.f, im = 0.f;
    for (int it = 0; it < 64; ++it) {
        int mm = (kz * it) & 63;
        float sv, cv; __sincosf((TWO_PI / 64.0f) * mm, &sv, &cv);
        float v = p[(size_t)it * 9];
        re += v * cv; im -= v * sv;
    }
    tA[m.tAo[lev] + idx] = make_float2(re, im);
}

// ---------------- forward y DFT (kept modes only, all levels) ----------------
__global__ void fwdy_kernel(const float2* __restrict__ tA, float2* __restrict__ tB, Meta m)
{
    int lev = find_lev(m.by);
    int n = m.n[lev], l1 = m.l1[lev], L = m.L[lev];
    int idx = (blockIdx.x - m.by[lev]) * 256 + threadIdx.x;
    int total = 8 * n * L * 45;
    if (idx >= total) return;
    int c45 = idx % 45; int tmp = idx / 45;
    int kyI = tmp % L; tmp /= L;
    int ix = tmp % n; int b = tmp / n;
    int ky = (kyI < l1) ? kyI : (n - L + kyI);
    const float2* p = tA + m.tAo[lev] + ((size_t)(b * n + ix) * n) * 45 + c45;
    float re = 0.f, im = 0.f;
    for (int iy = 0; iy < n; ++iy) {
        int mm = (ky * iy) & (n - 1);
        float sv, cv; __sincosf((TWO_PI / n) * mm, &sv, &cv);
        float2 a = p[(size_t)iy * 45];
        re += a.x * cv + a.y * sv;
        im += a.y * cv - a.x * sv;
    }
    tB[m.tBo[lev] + idx] = make_float2(re, im);
}

// ------- fused forward-x DFT + 9x9 complex mode mix (priority w4>w3>w2>w1), all levels -------
__global__ void fwdxmix_kernel(const float2* __restrict__ tB, float2* __restrict__ tD,
                               const float* __restrict__ w1, const float* __restrict__ w2,
                               const float* __restrict__ w3, const float* __restrict__ w4,
                               Meta m)
{
    __shared__ float2 sFzy[32 * 45];
    __shared__ float2 sF[10 * 45];
    int lev = find_lev(m.bxm);
    int n = m.n[lev], l1 = m.l1[lev], L = m.L[lev];
    int lb = blockIdx.x - m.bxm[lev];
    int kyI = lb % L;
    int b   = lb / L;
    int ky = (kyI < l1) ? kyI : (n - L + kyI);
    int nload = n * 45;
    for (int i = threadIdx.x; i < nload; i += blockDim.x) {
        int ix = i / 45, c = i % 45;
        sFzy[i] = tB[m.tBo[lev] + ((size_t)(b * n + ix) * L + kyI) * 45 + c];
    }
    __syncthreads();
    int nf = L * 45;
    for (int i = threadIdx.x; i < nf; i += blockDim.x) {
        int kxI = i / 45, c = i % 45;
        int kx = (kxI < l1) ? kxI : (n - L + kxI);
        float re = 0.f, im = 0.f;
        for (int ix = 0; ix < n; ++ix) {
            int mm = (kx * ix) & (n - 1);
            float sv, cv; __sincosf((TWO_PI / n) * mm, &sv, &cv);
            float2 a = sFzy[ix * 45 + c];
            re += a.x * cv + a.y * sv;
            im += a.y * cv - a.x * sv;
        }
        sF[i] = make_float2(re, im);
    }
    __syncthreads();
    bool ly = ky < l1, hy = ky >= n - l1;
    for (int i = threadIdx.x; i < nf; i += blockDim.x) {
        int kxI = i / 45, c = i % 45;
        int kz = c / 9, oc = c % 9;
        int kx = (kxI < l1) ? kxI : (n - L + kxI);
        bool lx = kx < l1, hx = kx >= n - l1;
        const float* w; int wx, wy;
        if (hx && hy)      { w = w4; wx = kx - (n - l1); wy = ky - (n - l1); }
        else if (lx && hy) { w = w3; wx = kx;            wy = ky - (n - l1); }
        else if (hx && ly) { w = w2; wx = kx - (n - l1); wy = ky; }
        else               { w = w1; wx = kx;            wy = ky; }
        const float* wb = w + (((size_t)oc * 5 + wx) * 5 + wy) * 10 + kz * 2;
        const float2* pf = &sF[kxI * 45 + kz * 9];
        float re = 0.f, im = 0.f;
        #pragma unroll
        for (int ic = 0; ic < 9; ++ic) {
            float2 a = pf[ic];
            float wr = wb[(size_t)ic * 2250];
            float wi = wb[(size_t)ic * 2250 + 1];
            re += a.x * wr - a.y * wi;
            im += a.x * wi + a.y * wr;
        }
        tD[m.tDo[lev] + (((size_t)(b * L + kxI) * L + kyI) * 5 + kz) * 9 + oc] = make_float2(re, im);
    }
}

// ---------------- inverse x (zero-padded modes -> full axis), all levels ----------------
__global__ void invx_kernel(const float2* __restrict__ tD, float2* __restrict__ tB, Meta m)
{
    int lev = find_lev(m.bix);
    int n = m.n[lev], l1 = m.l1[lev], L = m.L[lev];
    int idx = (blockIdx.x - m.bix[lev]) * 256 + threadIdx.x;
    int total = 8 * n * L * 45;
    if (idx >= total) return;
    int c45 = idx % 45; int tmp = idx / 45;
    int kyI = tmp % L; tmp /= L;
    int ix = tmp % n; int b = tmp / n;
    const float2* p = tD + m.tDo[lev] + ((size_t)b * L * L) * 45 + (size_t)kyI * 45 + c45;
    float re = 0.f, im = 0.f;
    for (int kxI = 0; kxI < L; ++kxI) {
        int kx = (kxI < l1) ? kxI : (n - L + kxI);
        int mm = (kx * ix) & (n - 1);
        float sv, cv; __sincosf((TWO_PI / n) * mm, &sv, &cv);
        float2 a = p[(size_t)kxI * L * 45];
        re += a.x * cv - a.y * sv;
        im += a.x * sv + a.y * cv;
    }
    tB[m.tBo[lev] + idx] = make_float2(re, im);
}

// ------- fused inverse-y + inverse-z(c2r) + ReLU + Linear, all levels -------
__global__ void invyz_kernel(const float2* __restrict__ tB, float* __restrict__ ud_all,
                             const float* __restrict__ lw, const float* __restrict__ lb,
                             Meta m)
{
    __shared__ float2 sG1[10 * 45];
    __shared__ float2 sG2[4 * 45];
    __shared__ float slw[81], slb[9];
    int lev = find_lev(m.biz);
    int n = m.n[lev], l1 = m.l1[lev], L = m.L[lev], NT = m.NT[lev];
    int TY = n / NT;
    int lb2 = blockIdx.x - m.biz[lev];
    int iyt = lb2 % NT;
    int ix  = (lb2 / NT) % n;
    int b   = lb2 / (NT * n);
    int iy0 = iyt * TY;
    if (threadIdx.x < 81) slw[threadIdx.x] = lw[threadIdx.x];
    if (threadIdx.x < 9)  slb[threadIdx.x] = lb[threadIdx.x];
    int nload = L * 45;
    for (int i = threadIdx.x; i < nload; i += blockDim.x)
        sG1[i] = tB[m.tBo[lev] + ((size_t)(b * n + ix) * L) * 45 + i];
    __syncthreads();
    int nf = TY * 45;
    for (int i = threadIdx.x; i < nf; i += blockDim.x) {
        int il = i / 45, c = i % 45;
        int iy = iy0 + il;
        float re = 0.f, im = 0.f;
        for (int kyI = 0; kyI < L; ++kyI) {
            int ky = (kyI < l1) ? kyI : (n - L + kyI);
            int mm = (ky * iy) & (n - 1);
            float sv, cv; __sincosf((TWO_PI / n) * mm, &sv, &cv);
            float2 a = sG1[kyI * 45 + c];
            re += a.x * cv - a.y * sv;
            im += a.x * sv + a.y * cv;
        }
        sG2[i] = make_float2(re, im);
    }
    __syncthreads();
    int t = threadIdx.x;
    if (t < TY * 64) {
        int il = t >> 6, it = t & 63;
        float inv_norm = 1.0f / ((float)n * (float)n * 64.0f);
        float cvz[5], svz[5];
        #pragma unroll
        for (int kz = 0; kz < 5; ++kz) {
            int mm = (kz * it) & 63;
            __sincosf((TWO_PI / 64.0f) * mm, &svz[kz], &cvz[kz]);
        }
        const float2* pg = &sG2[il * 45];
        float y[9];
        #pragma unroll
        for (int oc = 0; oc < 9; ++oc) {
            float v = 0.f;
            #pragma unroll
            for (int kz = 0; kz < 5; ++kz) {
                float2 a = pg[kz * 9 + oc];
                float term = a.x * cvz[kz] - a.y * svz[kz];
                v += (kz == 0 ? 1.0f : 2.0f) * term;
            }
            y[oc] = fmaxf(v * inv_norm, 0.f);
        }
        size_t ob = ((size_t)(m.soff[lev] + (b * n + ix) * n + iy0 + il) * 64 + it) * 9;
        #pragma unroll
        for (int o2 = 0; o2 < 9; ++o2) {
            float v = slb[o2];
            #pragma unroll
            for (int oc = 0; oc < 9; ++oc) v += y[oc] * slw[o2 * 9 + oc];
            ud_all[ob + o2] = v;
        }
    }
}

// ------- reconstruct: (x(+T0)+Us | Ud) -> even/odd interleave to [b,2n,2n,64,9] -------
__global__ void recon_kernel(const float* __restrict__ x, const float* __restrict__ Us,
                             const float* __restrict__ Ud, float* __restrict__ out,
                             const float* __restrict__ ree, const float* __restrict__ reo,
                             const float* __restrict__ roe, const float* __restrict__ roo,
                             const float* __restrict__ t0w, const float* __restrict__ t0b,
                             int n, int total, int apply_t0)
{
    __shared__ float s_m[4][162];
    __shared__ float st0[81], st0b[9];
    for (int i = threadIdx.x; i < 162; i += blockDim.x) {
        s_m[0][i] = ree[i]; s_m[1][i] = reo[i]; s_m[2][i] = roe[i]; s_m[3][i] = roo[i];
    }
    if (threadIdx.x < 81) st0[threadIdx.x] = t0w[threadIdx.x];
    if (threadIdx.x < 9)  st0b[threadIdx.x] = t0b[threadIdx.x];
    __syncthreads();
    int idx = blockIdx.x * blockDim.x + threadIdx.x;
    if (idx >= total) return;
    int it = idx & 63; int tmp = idx >> 6;
    int iy = tmp % n; tmp /= n;
    int ix = tmp % n; int b = tmp / n;
    float v[18];
    size_t ib = (size_t)idx * 9;
    if (apply_t0) {
        float xr[9];
        #pragma unroll
        for (int k = 0; k < 9; ++k) xr[k] = x[ib+k];
        #pragma unroll
        for (int o = 0; o < 9; ++o) {
            float r = st0b[o];
            #pragma unroll
            for (int i = 0; i < 9; ++i) r += xr[i] * st0[o*9+i];
            v[o] = r + Us[ib+o];
        }
    } else {
        #pragma unroll
        for (int k = 0; k < 9; ++k) v[k] = x[ib+k] + Us[ib+k];
    }
    #pragma unroll
    for (int k = 0; k < 9; ++k) v[9+k] = Ud[ib+k];
    int n2 = 2 * n;
    #pragma unroll
    for (int q = 0; q < 4; ++q) {
        int rx = q >> 1, ry = q & 1;
        size_t ob = ((((size_t)(b * n2 + 2*ix + rx) * n2) + 2*iy + ry) * 64 + it) * 9;
        const float* mm = s_m[q];
        #pragma unroll
        for (int oc = 0; oc < 9; ++oc) {
            float r = 0.f;
            #pragma unroll
            for (int k = 0; k < 18; ++k) r += v[k] * mm[k*9+oc];
            out[ob + oc] = r;
        }
    }
}

extern "C" void kernel_launch(void* const* d_in, const int* in_sizes, int n_in,
                              void* d_out, int out_size, void* d_ws, size_t ws_size,
                              hipStream_t stream)
{
    const float* x0    = (const float*)d_in[0];
    const float* ec_s  = (const float*)d_in[1];
    const float* ec_d  = (const float*)d_in[2];
    const float* rc_ee = (const float*)d_in[3];
    const float* rc_eo = (const float*)d_in[4];
    const float* rc_oe = (const float*)d_in[5];
    const float* rc_oo = (const float*)d_in[6];
    const float* w1    = (const float*)d_in[7];
    const float* w2    = (const float*)d_in[8];
    const float* w3    = (const float*)d_in[9];
    const float* w4    = (const float*)d_in[10];
    const float* A_Lo_w = (const float*)d_in[11];
    const float* A_Lo_b = (const float*)d_in[12];
    const float* B_cw  = (const float*)d_in[13];
    const float* B_cb  = (const float*)d_in[14];
    const float* B_lw  = (const float*)d_in[15];
    const float* B_lb  = (const float*)d_in[16];
    const float* C_cw  = (const float*)d_in[17];
    const float* C_cb  = (const float*)d_in[18];
    const float* C_lw  = (const float*)d_in[19];
    const float* C_lb  = (const float*)d_in[20];
    const float* T0_w  = (const float*)d_in[21];
    const float* T0_b  = (const float*)d_in[22];

    // ---- build meta ----
    Meta m;
    int ns_[6] = {32, 16, 8, 4, 2, 1};
    int az = 0, ay = 0, axm = 0, aix = 0, aiz = 0, acv = 0;
    int aS = 0, aA = 0, aB = 0, aD = 0;
    for (int l = 0; l < 6; ++l) {
        int n = ns_[l];
        int l1 = (n / 2 + 1 < 5) ? (n / 2 + 1) : 5;
        int L = (2 * l1 < n) ? 2 * l1 : n;
        int TY = (n < 4) ? n : 4;
        int NT = n / TY;
        int nh = (n + 1) / 2;
        m.n[l] = n; m.l1[l] = l1; m.L[l] = L; m.NT[l] = NT;
        m.soff[l] = aS; m.tAo[l] = aA; m.tBo[l] = aB; m.tDo[l] = aD;
        m.bz[l] = az; m.by[l] = ay; m.bxm[l] = axm; m.bix[l] = aix; m.biz[l] = aiz; m.bcv[l] = acv;
        az  += (8 * n * n * 45 + 255) / 256;
        ay  += (8 * n * L * 45 + 255) / 256;
        axm += 8 * L;
        aix += (8 * n * L * 45 + 255) / 256;
        aiz += 8 * n * NT;
        acv += (8 * n * nh * 64 + 255) / 256;
        aS += 8 * n * n; aA += 8 * n * n * 45; aB += 8 * n * L * 45; aD += 8 * L * L * 45;
    }
    m.bz[6] = az; m.by[6] = ay; m.bxm[6] = axm; m.bix[6] = aix; m.biz[6] = aiz; m.bcv[6] = acv;

    // ---- workspace carve ----
    float* ws = (float*)d_ws;
    size_t off = 0;
    auto alloc = [&](size_t nf) { float* p = ws + off; off += (nf + 3) & ~(size_t)3; return p; };
    size_t NSf = (size_t)aS * 576;      // total d/s/Ud/Us floats
    float* d_all  = alloc(NSf);
    float* s_all  = alloc(NSf);
    float* ud_all = alloc(NSf);
    float* us_all = alloc(NSf);
    float2* tA = (float2*)alloc((size_t)aA * 2);
    float2* tB = (float2*)alloc((size_t)aB * 2);
    float2* tD = (float2*)alloc((size_t)aD * 2);
    float* pingA = alloc((size_t)8 * 32 * 32 * 64 * 9);  // lev5,3,1 outputs (max 18.9MB)
    float* pingB = alloc((size_t)8 * 16 * 16 * 64 * 9);  // lev4,2 outputs

    const int BLK = 256;

    // ---- decompose chain (sequential) ----
    for (int lev = 0; lev < 6; ++lev) {
        int n = ns_[lev];
        const float* xin = (lev == 0) ? x0 : (s_all + (size_t)m.soff[lev-1] * 576);
        int total = 8 * n * n * 64;
        wavelet_kernel<<<(total + BLK - 1) / BLK, BLK, 0, stream>>>(
            xin, d_all + (size_t)m.soff[lev] * 576, s_all + (size_t)m.soff[lev] * 576,
            ec_d, ec_s, n, total);
    }

    // ---- batched FT pipeline + convs (all levels in one dispatch each) ----
    fwdz_kernel  <<<az,  BLK, 0, stream>>>(d_all, tA, m);
    fwdy_kernel  <<<ay,  BLK, 0, stream>>>(tA, tB, m);
    fwdxmix_kernel<<<axm, BLK, 0, stream>>>(tB, tD, w1, w2, w3, w4, m);
    invx_kernel  <<<aix, BLK, 0, stream>>>(tD, tB, m);
    invyz_kernel <<<aiz, BLK, 0, stream>>>(tB, ud_all, A_Lo_w, A_Lo_b, m);
    dim3 cgrid(acv, 2);
    conv2_kernel <<<cgrid, BLK, 0, stream>>>(s_all, ud_all, d_all, us_all,
                                             B_cw, B_cb, B_lw, B_lb,
                                             C_cw, C_cb, C_lw, C_lb, m);

    // ---- reconstruct chain (sequential; lev5 applies T0 inline) ----
    float* cur = nullptr;
    for (int lev = 5; lev >= 0; --lev) {
        int n = ns_[lev];
        int total = 8 * n * n * 64;
        const float* xin = (lev == 5) ? (s_all + (size_t)m.soff[5] * 576) : cur;
        float* outp = (lev == 0) ? (float*)d_out : ((lev & 1) ? pingA : pingB);
        recon_kernel<<<(total + BLK - 1) / BLK, BLK, 0, stream>>>(
            xin, us_all + (size_t)m.soff[lev] * 576, ud_all + (size_t)m.soff[lev] * 576, outp,
            rc_ee, rc_eo, rc_oe, rc_oo, T0_w, T0_b, n, total, (lev == 5) ? 1 : 0);
        cur = outp;
    }
}